// Round 1
// 750.706 us; speedup vs baseline: 1.2031x; 1.2031x over previous
//
#include <hip/hip_runtime.h>
#include <hip/hip_bf16.h>
#include <stdint.h>
#include <stddef.h>

// Problem dims (fixed by reference)
#define BSZ  8192
#define DIN  1024
#define HH   4096
#define DOUT 1024

// Old-kernel GEMM tile config (kept for fallback paths)
#define BM 128
#define BN 128
#define BK 32

typedef __attribute__((ext_vector_type(8))) short   frag8;   // 8 bf16 (4 VGPRs)
typedef __attribute__((ext_vector_type(4))) float   f32x4;   // MFMA C/D
typedef __attribute__((ext_vector_type(8))) unsigned short u16x8;

__device__ __forceinline__ unsigned short f2bf_rne(float f) {
    union { float f; uint32_t u; } c; c.f = f;
    uint32_t u = c.u;
    return (unsigned short)((u + 0x7FFFu + ((u >> 16) & 1u)) >> 16);
}

__device__ __forceinline__ void cvt8(const float* __restrict__ s, unsigned short* __restrict__ d) {
    f32x4 v0 = *(const f32x4*)s;
    f32x4 v1 = *(const f32x4*)(s + 4);
    u16x8 o;
    o[0] = f2bf_rne(v0[0]); o[1] = f2bf_rne(v0[1]); o[2] = f2bf_rne(v0[2]); o[3] = f2bf_rne(v0[3]);
    o[4] = f2bf_rne(v1[0]); o[5] = f2bf_rne(v1[1]); o[6] = f2bf_rne(v1[2]); o[7] = f2bf_rne(v1[3]);
    *(u16x8*)d = o;
}

// Single-array f32->bf16 (mid-ws fallback only)
__global__ __launch_bounds__(256)
void cvt_f32_bf16(const float* __restrict__ src, unsigned short* __restrict__ dst, long n) {
    long i = ((long)blockIdx.x * 256 + threadIdx.x) * 8;
    if (i < n) cvt8(src + i, dst + i);
}

// Fallback combined converter (kept for compatibility; not used on fast path)
__global__ __launch_bounds__(256)
void cvt_all5(const float* __restrict__ s0, unsigned short* __restrict__ d0, long n0,
              const float* __restrict__ s1, unsigned short* __restrict__ d1, long n1,
              const float* __restrict__ s2, unsigned short* __restrict__ d2, long n2,
              const float* __restrict__ s3, unsigned short* __restrict__ d3, long n3,
              const float* __restrict__ s4, unsigned short* __restrict__ d4, long n4) {
    long i = ((long)blockIdx.x * 256 + threadIdx.x) * 8;
    if (i < n0) { cvt8(s0 + i, d0 + i); return; } i -= n0;
    if (i < n1) { cvt8(s1 + i, d1 + i); return; } i -= n1;
    if (i < n2) { cvt8(s2 + i, d2 + i); return; } i -= n2;
    if (i < n3) { cvt8(s3 + i, d3 + i); return; } i -= n3;
    if (i < n4) { cvt8(s4 + i, d4 + i); }
}

// Fast-path converter: convert AND pack concat operands in one dispatch.
//   X[8192,1024] + state[8192,4096] -> XS bf16 [8192, 5120]
//   W_in[4096,1024] + W_rec[4096,4096] -> W1 bf16 [4096, 5120]
//   W_out[1024,4096] -> Wob bf16
// Unit of work = 8 contiguous f32 elements (16B bf16 store, aligned).
#define NX8  ((long)BSZ * DIN / 8)     // 1048576
#define NS8  ((long)BSZ * HH / 8)      // 4194304
#define NWI8 ((long)HH * DIN / 8)      // 524288
#define NWR8 ((long)HH * HH / 8)       // 2097152
#define NWO8 ((long)DOUT * HH / 8)     // 524288
#define NCVT_BLOCKS 32768              // (NX8+NS8+NWI8+NWR8+NWO8)/256

__global__ __launch_bounds__(256)
void cvt_pack(const float* __restrict__ X, const float* __restrict__ S,
              const float* __restrict__ Wi, const float* __restrict__ Wr,
              const float* __restrict__ Wo,
              unsigned short* __restrict__ XS, unsigned short* __restrict__ W1,
              unsigned short* __restrict__ Wob) {
    long i = (long)blockIdx.x * 256 + threadIdx.x;
    if (i < NX8)  { long r = i >> 7, c = i & 127; cvt8(X + i * 8, XS + r * 5120 + c * 8); return; }
    i -= NX8;
    if (i < NS8)  { long r = i >> 9, c = i & 511; cvt8(S + i * 8, XS + r * 5120 + 1024 + c * 8); return; }
    i -= NS8;
    if (i < NWI8) { long r = i >> 7, c = i & 127; cvt8(Wi + i * 8, W1 + r * 5120 + c * 8); return; }
    i -= NWI8;
    if (i < NWR8) { long r = i >> 9, c = i & 511; cvt8(Wr + i * 8, W1 + r * 5120 + 1024 + c * 8); return; }
    i -= NWR8;
    if (i < NWO8) { cvt8(Wo + i * 8, Wob + i * 8); }
}

__device__ __forceinline__ void glds16(const unsigned short* __restrict__ gp, short* lp) {
    __builtin_amdgcn_global_load_lds(
        (const __attribute__((address_space(1))) uint32_t*)gp,
        (__attribute__((address_space(3))) uint32_t*)lp, 16, 0, 0);
}

__device__ __forceinline__ void glds16v(const unsigned short* __restrict__ gp, void* lp) {
    __builtin_amdgcn_global_load_lds(
        (const __attribute__((address_space(1))) uint32_t*)gp,
        (__attribute__((address_space(3))) uint32_t*)lp, 16, 0, 0);
}

// ============================================================================
// NEW: 256x256-tile, BK=64, 8-wave (2M x 4N), 8-phase counted-vmcnt GEMM.
// C[m,n] = relu( sum_k A[m,k]*B[n,k] + bias1[n] (+bias2[n]) ), optional bf16 copy.
//
// LDS (128 KiB, dynamic): buf b in {0,1}: A halves (2x 16KiB) | B halves (2x 16KiB).
//   half = 128 rows x 64 cols bf16, XOR-swizzled: 16B-chunk x of row r holds data
//   chunk x ^ (r&7)  (involution; inverse applied to the gload_lds GLOBAL src addr,
//   LDS dest stays linear -> rule #21 both-sides-or-neither).
//
// Schedule per K-tile kt (4 phases, phase p = m-quadrant p, 16 MFMA each):
//   p0: read 8 B-frags (whole K-tile, held in regs) + A-quad0;
//       stage A(kt+1) -> other buf        [4 loads]   (A region free: last read kt-1 p3)
//   p1: read A-quad1; stage B(kt+2) h0 -> THIS buf    [2 loads]   (B region free after p0)
//   p2: read A-quad2; stage B(kt+2) h1 -> THIS buf    [2 loads]
//   p3: read A-quad3; s_waitcnt vmcnt(4) (forces A(kt+1)+B(kt+1) landed; leaves
//       B(kt+2)'s 4 loads in flight -> never drains to 0 in the loop)
//   each phase: {reads; stages; s_barrier; setprio(1); 16 MFMA; setprio(0); [vmcnt]; s_barrier}
// Accumulation order is bitwise identical to the 128x128 kernel (k ascending).
// ============================================================================
template<int C>
__device__ __forceinline__ void ktile_group(
    int kA, int kB,
    const unsigned short* __restrict__ gA, size_t a64,
    const unsigned short* __restrict__ gB, size_t b64,
    const char* Ar0, const char* Br0, char* ldsw,
    int aoff, int boff, f32x4 (&acc)[8][4])
{
    const char* Ar = Ar0 + C * 65536;
    const char* Br = Br0 + C * 65536;
    char* wA = ldsw + (C ^ 1) * 65536;          // A region of the other buffer
    char* wB = ldsw + C * 65536 + 32768;        // B region of this (read) buffer
    const unsigned short* gAk = gA + kA * 64;
    const unsigned short* gBk = gB + kB * 64;

    frag8 bfr[4][2];
    frag8 af[2][2];
#pragma unroll
    for (int p = 0; p < 4; ++p) {
        if (p == 0) {
#pragma unroll
            for (int ni = 0; ni < 4; ni++)
#pragma unroll
                for (int ks = 0; ks < 2; ks++)
                    bfr[ni][ks] = *(const frag8*)(Br + ni * 2048 + (boff ^ (ks << 6)));
        }
#pragma unroll
        for (int m2 = 0; m2 < 2; m2++)
#pragma unroll
            for (int ks = 0; ks < 2; ks++)
                af[m2][ks] = *(const frag8*)(Ar + (p * 2 + m2) * 2048 + (aoff ^ (ks << 6)));

        if (p == 0) {
            glds16v(gAk,           wA);
            glds16v(gAk + a64,     wA + 8192);
            glds16v(gAk + 2 * a64, wA + 16384);
            glds16v(gAk + 3 * a64, wA + 16384 + 8192);
        } else if (p == 1) {
            glds16v(gBk,           wB);
            glds16v(gBk + b64,     wB + 8192);
        } else if (p == 2) {
            glds16v(gBk + 2 * b64, wB + 16384);
            glds16v(gBk + 3 * b64, wB + 16384 + 8192);
        }

        __builtin_amdgcn_s_barrier();
        __builtin_amdgcn_s_setprio(1);
#pragma unroll
        for (int m2 = 0; m2 < 2; m2++)
#pragma unroll
            for (int ni = 0; ni < 4; ni++)
#pragma unroll
                for (int ks = 0; ks < 2; ks++)
                    acc[p * 2 + m2][ni] = __builtin_amdgcn_mfma_f32_16x16x32_bf16(
                        af[m2][ks], bfr[ni][ks], acc[p * 2 + m2][ni], 0, 0, 0);
        __builtin_amdgcn_s_setprio(0);
        if (p == 3) asm volatile("s_waitcnt vmcnt(4)" ::: "memory");
        __builtin_amdgcn_s_barrier();
    }
}

__global__ __launch_bounds__(512, 2)
void gemm256_relu(const unsigned short* __restrict__ A, int lda,
                  const unsigned short* __restrict__ B, int ldb, int K,
                  const float* __restrict__ bias1, const float* __restrict__ bias2,
                  float* __restrict__ C, unsigned short* __restrict__ Cb, int ncols) {
    extern __shared__ char lds[];   // 131072 bytes

    const int tid  = threadIdx.x;
    const int wave = tid >> 6, lane = tid & 63;
    const int quad = lane >> 4, l16 = lane & 15;
    const int wm2  = wave >> 2, wn4 = wave & 3;     // 2M x 4N wave grid
    const int tile_m = blockIdx.y * 256;
    const int tile_n = blockIdx.x * 256;
    const int NT = K >> 6;                          // K-tiles (even for all our shapes)

    // Staging source (per-thread): slot s = tid (+512) -> row r0 (+64), swizzled chunk c0
    const int r0 = tid >> 3;
    const int c0 = (tid & 7) ^ (r0 & 7);
    const unsigned short* gA = A + (size_t)(tile_m + r0) * lda + c0 * 8;
    const unsigned short* gB = B + (size_t)(tile_n + r0) * ldb + c0 * 8;
    const size_t a64 = (size_t)64 * lda, b64 = (size_t)64 * ldb;

    // Read-side per-lane byte offsets (within a 16KiB half): row*128 + swizzled chunk*16
    const int swz  = (quad ^ (l16 & 7)) << 4;
    const int aoff = l16 * 128 + swz;
    const int boff = ((wn4 & 1) * 64 + l16) * 128 + swz;
    const char* Ar0 = lds + wm2 * 16384;                    // this wave's A half, buf0
    const char* Br0 = lds + 32768 + (wn4 >> 1) * 16384;     // this wave's B half, buf0
    char* ldsw = lds + wave * 1024;                         // wave-uniform stage base

    // Prologue: T0 (A+B) -> buf0; B of T1 -> buf1. 12 loads; vmcnt(4) = T0 landed,
    // B(T1) left in flight (steady-state invariant: 4 loads outstanding at each barrier).
    glds16v(gA,           ldsw);
    glds16v(gA + a64,     ldsw + 8192);
    glds16v(gA + 2 * a64, ldsw + 16384);
    glds16v(gA + 3 * a64, ldsw + 16384 + 8192);
    glds16v(gB,           ldsw + 32768);
    glds16v(gB + b64,     ldsw + 32768 + 8192);
    glds16v(gB + 2 * b64, ldsw + 32768 + 16384);
    glds16v(gB + 3 * b64, ldsw + 32768 + 16384 + 8192);
    {
        const unsigned short* gB1 = gB + 64;   // K-tile 1
        glds16v(gB1,           ldsw + 65536 + 32768);
        glds16v(gB1 + b64,     ldsw + 65536 + 32768 + 8192);
        glds16v(gB1 + 2 * b64, ldsw + 65536 + 32768 + 16384);
        glds16v(gB1 + 3 * b64, ldsw + 65536 + 32768 + 16384 + 8192);
    }
    asm volatile("s_waitcnt vmcnt(4)" ::: "memory");
    __builtin_amdgcn_s_barrier();

    f32x4 acc[8][4] = {};

    for (int kt = 0; kt < NT; kt += 2) {
        int kA0 = kt + 1;                                  // < NT always here
        int kB0 = kt + 2; if (kB0 >= NT) kB0 -= NT;        // wrap: harmless extra load
        ktile_group<0>(kA0, kB0, gA, a64, gB, b64, Ar0, Br0, ldsw, aoff, boff, acc);
        int kA1 = kt + 2; if (kA1 >= NT) kA1 -= NT;
        int kB1 = kt + 3; if (kB1 >= NT) kB1 -= NT;
        ktile_group<1>(kA1, kB1, gA, a64, gB, b64, Ar0, Br0, ldsw, aoff, boff, acc);
    }

    // Epilogue. C/D layout (verified m89/m91): n = l16, m = quad*4 + reg.
#pragma unroll
    for (int ni = 0; ni < 4; ni++) {
        const int n = tile_n + wn4 * 64 + ni * 16 + l16;
        float bv = bias1[n];
        if (bias2) bv += bias2[n];
#pragma unroll
        for (int mi = 0; mi < 8; mi++) {
            const int m0 = tile_m + wm2 * 128 + mi * 16 + quad * 4;
#pragma unroll
            for (int r = 0; r < 4; r++) {
                float v = acc[mi][ni][r] + bv;
                v = v > 0.f ? v : 0.f;
                const size_t idx = (size_t)(m0 + r) * ncols + n;
                C[idx] = v;
                if (Cb) Cb[idx] = f2bf_rne(v);
            }
        }
    }
}

// ============================================================================
// OLD 128x128 kernel, kept verbatim for mid/no-ws fallback paths.
// ============================================================================
template <bool A_BF16, bool B_BF16>
__global__ __launch_bounds__(256)
void gemm_bt_relu(const void* __restrict__ A1, int lda1,
                  const void* __restrict__ A2, int lda2,
                  const void* __restrict__ B1, int ldb1,
                  const void* __restrict__ B2, int ldb2,
                  int Ksplit, int K,
                  const float* __restrict__ bias1, const float* __restrict__ bias2,
                  float* __restrict__ C, unsigned short* __restrict__ Cb, int N) {
    __shared__ short As[BM * BK];
    __shared__ short Bs[BN * BK];

    const int tid    = threadIdx.x;
    const int tile_m = blockIdx.y * BM;
    const int tile_n = blockIdx.x * BN;
    const int wave = tid >> 6, lane = tid & 63;
    const int quad = lane >> 4, l16 = lane & 15;
    const int wm = (wave >> 1) * 64;
    const int wn = (wave & 1) * 64;
    const int sr = tid >> 2;
    const int sc = (tid & 3) * 8;

    short* ldsA0 = &As[tid * 8]; short* ldsA1 = &As[(256 + tid) * 8];
    short* ldsB0 = &Bs[tid * 8]; short* ldsB1 = &Bs[(256 + tid) * 8];

    f32x4 acc[4][4] = {};

    for (int phase = 0; phase < 2; ++phase) {
        const int kmax = phase ? (K - Ksplit) : Ksplit;
        if (kmax <= 0) continue;
        const void* Ap = phase ? A2 : A1; const int la = phase ? lda2 : lda1;
        const void* Bp = phase ? B2 : B1; const int lb = phase ? ldb2 : ldb1;

        const unsigned short *ga = nullptr, *gb = nullptr;
        const float *fa = nullptr, *fb = nullptr;
        if (A_BF16) ga = (const unsigned short*)Ap + (size_t)(tile_m + sr) * la + sc;
        else        fa = (const float*)Ap          + (size_t)(tile_m + sr) * la + sc;
        if (B_BF16) gb = (const unsigned short*)Bp + (size_t)(tile_n + sr) * lb + sc;
        else        fb = (const float*)Bp          + (size_t)(tile_n + sr) * lb + sc;
        const size_t la64 = (size_t)64 * la, lb64 = (size_t)64 * lb;

        for (int kk = 0; kk < kmax; kk += BK) {
            __syncthreads();
            if (A_BF16) {
                glds16(ga, ldsA0); glds16(ga + la64, ldsA1); ga += BK;
            } else {
                unsigned short t0[8], t1[8];
                cvt8(fa, t0); cvt8(fa + la64, t1); fa += BK;
                *(u16x8*)ldsA0 = *(u16x8*)t0; *(u16x8*)ldsA1 = *(u16x8*)t1;
            }
            if (B_BF16) {
                glds16(gb, ldsB0); glds16(gb + lb64, ldsB1); gb += BK;
            } else {
                unsigned short t0[8], t1[8];
                cvt8(fb, t0); cvt8(fb + lb64, t1); fb += BK;
                *(u16x8*)ldsB0 = *(u16x8*)t0; *(u16x8*)ldsB1 = *(u16x8*)t1;
            }
            __syncthreads();

            frag8 af2[4], bfr[4];
#pragma unroll
            for (int i = 0; i < 4; i++)
                af2[i] = *(const frag8*)&As[(wm + i * 16 + l16) * BK + quad * 8];
#pragma unroll
            for (int i = 0; i < 4; i++)
                bfr[i] = *(const frag8*)&Bs[(wn + i * 16 + l16) * BK + quad * 8];
#pragma unroll
            for (int mi = 0; mi < 4; mi++)
#pragma unroll
                for (int ni = 0; ni < 4; ni++)
                    acc[mi][ni] = __builtin_amdgcn_mfma_f32_16x16x32_bf16(
                        af2[mi], bfr[ni], acc[mi][ni], 0, 0, 0);
        }
    }

#pragma unroll
    for (int mi = 0; mi < 4; mi++) {
        const int m0 = tile_m + wm + mi * 16 + quad * 4;
#pragma unroll
        for (int ni = 0; ni < 4; ni++) {
            const int n = tile_n + wn + ni * 16 + l16;
            float bv = bias1[n];
            if (bias2) bv += bias2[n];
#pragma unroll
            for (int r = 0; r < 4; r++) {
                float v = acc[mi][ni][r] + bv;
                v = v > 0.f ? v : 0.f;
                const size_t idx = (size_t)(m0 + r) * N + n;
                C[idx] = v;
                if (Cb) Cb[idx] = f2bf_rne(v);
            }
        }
    }
}

extern "C" void kernel_launch(void* const* d_in, const int* in_sizes, int n_in,
                              void* d_out, int out_size, void* d_ws, size_t ws_size,
                              hipStream_t stream) {
    const float* X     = (const float*)d_in[0];
    const float* state = (const float*)d_in[1];
    const float* W_in  = (const float*)d_in[2];
    const float* b_in  = (const float*)d_in[3];
    const float* W_rec = (const float*)d_in[4];
    const float* b_rec = (const float*)d_in[5];
    const float* W_out = (const float*)d_in[6];
    const float* b_out = (const float*)d_in[7];

    float* out       = (float*)d_out;                       // [8192,1024]
    float* new_state = out + (size_t)BSZ * DOUT;            // [8192,4096]

    const size_t nX = (size_t)BSZ * DIN, nS = (size_t)BSZ * HH;
    const size_t nWin = (size_t)HH * DIN, nWrec = (size_t)HH * HH, nWout = (size_t)DOUT * HH;

    // Fast-path ws layout (all bf16, packed concat):
    //   XS [8192,5120] | W1 [4096,5120] | Wob [1024,4096] | NSb [8192,4096]
    const size_t offXS = 0;
    const size_t offW1 = offXS + (size_t)BSZ * (DIN + HH) * 2;   //  83,886,080
    const size_t offWo = offW1 + (size_t)HH  * (DIN + HH) * 2;   // 125,829,120
    const size_t offNS = offWo + (size_t)DOUT * HH * 2;          // 134,217,728
    const size_t need_full = offNS + nS * 2;                     // 201,326,592 (== old need_full)
    const size_t need_mid = nS * 2 + nWout * 2;                  // NSb + Woutb (~72 MiB)

    char* ws = (char*)d_ws;
    const dim3 blk(256);

    if (ws_size >= need_full) {
        unsigned short* XSb = (unsigned short*)(ws + offXS);
        unsigned short* W1b = (unsigned short*)(ws + offW1);
        unsigned short* Wob = (unsigned short*)(ws + offWo);
        unsigned short* NSb = (unsigned short*)(ws + offNS);

        static bool s_attr = false;
        if (!s_attr) {
            hipFuncSetAttribute(reinterpret_cast<const void*>(gemm256_relu),
                                hipFuncAttributeMaxDynamicSharedMemorySize, 131072);
            s_attr = true;
        }

        cvt_pack<<<dim3(NCVT_BLOCKS), blk, 0, stream>>>(
            X, state, W_in, W_rec, W_out, XSb, W1b, Wob);
        // gemm1: new_state = relu(XS @ W1^T + b_in + b_rec)   [8192 x 4096], K=5120
        gemm256_relu<<<dim3(HH / 256, BSZ / 256), dim3(512), 131072, stream>>>(
            XSb, DIN + HH, W1b, DIN + HH, DIN + HH, b_in, b_rec, new_state, NSb, HH);
        // gemm2: out = relu(NS @ W_out^T + b_out)             [8192 x 1024], K=4096
        gemm256_relu<<<dim3(DOUT / 256, BSZ / 256), dim3(512), 131072, stream>>>(
            NSb, HH, Wob, HH, HH, b_out, nullptr, out, nullptr, DOUT);
    } else if (ws_size >= need_mid) {
        const dim3 g1(HH / BN, BSZ / BM);
        const dim3 g2(DOUT / BN, BSZ / BM);
        unsigned short* NSb   = (unsigned short*)ws;
        unsigned short* Woutb = (unsigned short*)(ws + nS * 2);
        cvt_f32_bf16<<<dim3((unsigned)((nWout / 8 + 255) / 256)), blk, 0, stream>>>(
            W_out, Woutb, (long)nWout);
        gemm_bt_relu<false, false><<<g1, blk, 0, stream>>>(
            X, DIN, state, HH, W_in, DIN, W_rec, HH, DIN, DIN + HH,
            b_in, b_rec, new_state, NSb, HH);
        gemm_bt_relu<true, true><<<g2, blk, 0, stream>>>(
            NSb, HH, NSb, HH, Woutb, HH, Woutb, HH, HH, HH,
            b_out, nullptr, out, nullptr, DOUT);
    } else {
        const dim3 g1(HH / BN, BSZ / BM);
        const dim3 g2(DOUT / BN, BSZ / BM);
        gemm_bt_relu<false, false><<<g1, blk, 0, stream>>>(
            X, DIN, state, HH, W_in, DIN, W_rec, HH, DIN, DIN + HH,
            b_in, b_rec, new_state, nullptr, HH);
        gemm_bt_relu<false, false><<<g2, blk, 0, stream>>>(
            new_state, HH, new_state, HH, W_out, HH, W_out, HH, HH, HH,
            b_out, nullptr, out, nullptr, DOUT);
    }
}